// Round 1
// baseline (2089.635 us; speedup 1.0000x reference)
//
#include <hip/hip_runtime.h>

// Fused 2-layer GRU scan, persistent kernel.
// B=256,T=1024,F=64,U=128. 16 blocks x 512 threads; block owns 16 batch rows
// through BOTH layers for all 1024 steps (seq1 never materialized).
// Wave w owns units [16w,16w+16): its z/r/h columns -> gating is wave-local.
// U1/W2/U2 as bf16 MFMA B-frags in registers (144 VGPR/thread); W1 pre-swizzled
// in LDS; h state fp32 in regs, bf16 only at MFMA inputs via padded LDS.

#define TT 1024
#define FF 64
#define G3 384

typedef __attribute__((ext_vector_type(8))) __bf16 bf16x8;
typedef __attribute__((ext_vector_type(4))) float f32x4;

#define MFMA(a, b, c) __builtin_amdgcn_mfma_f32_16x16x32_bf16((a), (b), (c), 0, 0, 0)

__device__ __forceinline__ float sigf(float x) { return 1.0f / (1.0f + __expf(-x)); }

__device__ __forceinline__ bf16x8 ldsfrag(const __bf16* p) {
    return *(const bf16x8*)p;
}

__global__ __launch_bounds__(512, 2) void gru_fused(
    const float* __restrict__ x,   // [B,T,F]
    const float* __restrict__ W1,  // [F,3U]
    const float* __restrict__ U1,  // [U,3U]
    const float* __restrict__ b1,  // [2,3U]
    const float* __restrict__ W2,  // [U,3U]
    const float* __restrict__ U2,  // [U,3U]
    const float* __restrict__ b2,  // [2,3U]
    float* __restrict__ out)       // [x(256x128), state1, state2] fp32
{
    const int tid  = threadIdx.x;
    const int wave = tid >> 6;
    const int lane = tid & 63;
    const int quad = lane >> 4;
    const int lc   = lane & 15;         // A row / C col index
    const int u    = wave * 16 + lc;    // this thread's unit column (0..127)
    const int row0 = blockIdx.x * 16;

    // LDS: W1 frags 48KB + h1 dbuf 8.5KB + h2 4.25KB + x dbuf 4.5KB = ~66KB
    __shared__ __align__(16) __bf16 w1s[3 * 2 * 8 * 64 * 8]; // [g][kt][wave][lane][j]
    __shared__ __align__(16) __bf16 h1s[2][16][136];         // pad 128->136: 2-way banks (free)
    __shared__ __align__(16) __bf16 h2s[16][136];
    __shared__ __align__(16) __bf16 xs[2][16][72];           // pad 64->72

    for (int i = tid; i < 2 * 16 * 136; i += 512) ((__bf16*)h1s)[i] = (__bf16)0.f;
    for (int i = tid; i < 16 * 136; i += 512) ((__bf16*)h2s)[i] = (__bf16)0.f;

    // W1 -> LDS, pre-swizzled into B-frag order: elem j of lane l, wave w, (g,kt)
    // holds W1[kt*32 + (l>>4)*8 + j][g*128 + w*16 + (l&15)]
    for (int e = 0; e < 48; e++) {
        int f = tid * 48 + e;
        int j = f & 7, l = (f >> 3) & 63, w = (f >> 9) & 7, kt = (f >> 12) & 1, g = f >> 13;
        w1s[f] = (__bf16)W1[(kt * 32 + (l >> 4) * 8 + j) * G3 + g * 128 + w * 16 + (l & 15)];
    }

    // Recurrent weights as register-resident B-frags.
    // B-frag layout (16x16x32): lane holds B[k = quad*8+j + 32*kt][n = colbase + lc]
    bf16x8 U1B[3][4], W2B[3][4], U2B[3][4];
#pragma unroll
    for (int g = 0; g < 3; g++)
#pragma unroll
        for (int kt = 0; kt < 4; kt++) {
            bf16x8 a, b, c;
#pragma unroll
            for (int j = 0; j < 8; j++) {
                int k = kt * 32 + quad * 8 + j;
                int col = g * 128 + u;
                a[j] = (__bf16)U1[k * G3 + col];
                b[j] = (__bf16)W2[k * G3 + col];
                c[j] = (__bf16)U2[k * G3 + col];
            }
            U1B[g][kt] = a; W2B[g][kt] = b; U2B[g][kt] = c;
        }

    // Biases (all-zero in this problem, but honored). z/r input+recurrent biases fold.
    const float c1z = b1[0 * G3 + u] + b1[1 * G3 + u];
    const float c1r = b1[0 * G3 + 128 + u] + b1[1 * G3 + 128 + u];
    const float b1ih = b1[0 * G3 + 256 + u];
    const float b1rh = b1[1 * G3 + 256 + u];
    const float c2z = b2[0 * G3 + u] + b2[1 * G3 + u];
    const float c2r = b2[0 * G3 + 128 + u] + b2[1 * G3 + 128 + u];
    const float b2ih = b2[0 * G3 + 256 + u];
    const float b2rh = b2[1 * G3 + 256 + u];

    // x staging: thread -> (row xm, cols xc..xc+1)
    const int xm = tid >> 5;
    const int xc = (tid & 31) * 2;
    {
        const float* px = &x[(size_t)(row0 + xm) * (TT * FF) + xc];
        xs[0][xm][xc]     = (__bf16)px[0];
        xs[0][xm][xc + 1] = (__bf16)px[1];
    }

    float h1c[4] = {0.f, 0.f, 0.f, 0.f}; // fp32 state, C-layout (row quad*4+i, col u)
    float h2c[4] = {0.f, 0.f, 0.f, 0.f};

    __syncthreads();

    for (int t = 0; t < TT; t++) {
        // ph1: prefetch x(t+1) from global (latency hidden across the step)
        float pf0 = 0.f, pf1 = 0.f;
        if (t + 1 < TT) {
            const float* px = &x[(size_t)(row0 + xm) * (TT * FF) + (size_t)(t + 1) * FF + xc];
            pf0 = px[0]; pf1 = px[1];
        }

        // ph2: xw1(t) = x(t)@W1 (+biases as C-init). K=64 -> 2 ktiles.
        f32x4 z1 = {c1z, c1z, c1z, c1z};
        f32x4 r1 = {c1r, c1r, c1r, c1r};
        f32x4 xh1 = {b1ih, b1ih, b1ih, b1ih};
#pragma unroll
        for (int kt = 0; kt < 2; kt++) {
            bf16x8 xa = ldsfrag(&xs[t & 1][lc][kt * 32 + quad * 8]);
            bf16x8 wz = ldsfrag(&w1s[(((0 * 2 + kt) * 8 + wave) * 64 + lane) * 8]);
            bf16x8 wr = ldsfrag(&w1s[(((1 * 2 + kt) * 8 + wave) * 64 + lane) * 8]);
            bf16x8 wh = ldsfrag(&w1s[(((2 * 2 + kt) * 8 + wave) * 64 + lane) * 8]);
            z1 = MFMA(xa, wz, z1);
            r1 = MFMA(xa, wr, r1);
            xh1 = MFMA(xa, wh, xh1);
        }

        // ph3: rec2 = h2(t-1)@U2 (independent of layer1's critical path)
        f32x4 z2 = {c2z, c2z, c2z, c2z};
        f32x4 r2 = {c2r, c2r, c2r, c2r};
        f32x4 rh2 = {b2rh, b2rh, b2rh, b2rh};
#pragma unroll
        for (int kt = 0; kt < 4; kt++) {
            bf16x8 ha = ldsfrag(&h2s[lc][kt * 32 + quad * 8]);
            z2 = MFMA(ha, U2B[0][kt], z2);
            r2 = MFMA(ha, U2B[1][kt], r2);
            rh2 = MFMA(ha, U2B[2][kt], rh2);
        }

        // ph4: rec1 = h1(t-1)@U1  [critical path]
        f32x4 rh1 = {b1rh, b1rh, b1rh, b1rh};
#pragma unroll
        for (int kt = 0; kt < 4; kt++) {
            bf16x8 ha = ldsfrag(&h1s[(t + 1) & 1][lc][kt * 32 + quad * 8]);
            z1 = MFMA(ha, U1B[0][kt], z1);
            r1 = MFMA(ha, U1B[1][kt], r1);
            rh1 = MFMA(ha, U1B[2][kt], rh1);
        }

        // ph5: layer-1 gates (fp32). hh = relu(xh + r*rh); h = z*h + (1-z)*hh
#pragma unroll
        for (int i = 0; i < 4; i++) {
            float zf = sigf(z1[i]);
            float rf = sigf(r1[i]);
            float hh = fmaxf(xh1[i] + rf * rh1[i], 0.f);
            h1c[i] = zf * h1c[i] + (1.f - zf) * hh;
        }

        // ph6: stage x(t+1) (double-buffered, no race with ph2 readers of buf t&1)
        if (t + 1 < TT) {
            xs[(t + 1) & 1][xm][xc]     = (__bf16)pf0;
            xs[(t + 1) & 1][xm][xc + 1] = (__bf16)pf1;
        }

        // ph7: publish h1(t) (double-buffered vs ph4 readers of old h1)
#pragma unroll
        for (int i = 0; i < 4; i++)
            h1s[t & 1][quad * 4 + i][u] = (__bf16)h1c[i];

        __syncthreads(); // barrier 1: h1(t) + x(t+1) visible

        // ph8: xw2 = h1(t)@W2 ; z/r accumulate into rec2 accs
        f32x4 xh2 = {b2ih, b2ih, b2ih, b2ih};
#pragma unroll
        for (int kt = 0; kt < 4; kt++) {
            bf16x8 ha = ldsfrag(&h1s[t & 1][lc][kt * 32 + quad * 8]);
            z2 = MFMA(ha, W2B[0][kt], z2);
            r2 = MFMA(ha, W2B[1][kt], r2);
            xh2 = MFMA(ha, W2B[2][kt], xh2);
        }

        // ph9: layer-2 gates + publish h2(t)
#pragma unroll
        for (int i = 0; i < 4; i++) {
            float zf = sigf(z2[i]);
            float rf = sigf(r2[i]);
            float hh = fmaxf(xh2[i] + rf * rh2[i], 0.f);
            h2c[i] = zf * h2c[i] + (1.f - zf) * hh;
            h2s[quad * 4 + i][u] = (__bf16)h2c[i];
        }

        __syncthreads(); // barrier 2: h2(t) visible for next step's ph3
    }

    // Epilogue: out = [x = h2(T-1), state1 = h1(T-1), state2 = h2(T-1)]
#pragma unroll
    for (int i = 0; i < 4; i++) {
        int r = row0 + quad * 4 + i;
        out[(size_t)r * 128 + u]         = h2c[i];
        out[32768 + (size_t)r * 128 + u] = h1c[i];
        out[65536 + (size_t)r * 128 + u] = h2c[i];
    }
}

extern "C" void kernel_launch(void* const* d_in, const int* in_sizes, int n_in,
                              void* d_out, int out_size, void* d_ws, size_t ws_size,
                              hipStream_t stream) {
    const float* x  = (const float*)d_in[0];
    const float* W1 = (const float*)d_in[1];
    const float* U1 = (const float*)d_in[2];
    const float* b1 = (const float*)d_in[3];
    const float* W2 = (const float*)d_in[4];
    const float* U2 = (const float*)d_in[5];
    const float* b2 = (const float*)d_in[6];
    float* out = (float*)d_out;
    gru_fused<<<dim3(16), dim3(512), 0, stream>>>(x, W1, U1, b1, W2, U2, b2, out);
}